// Round 3
// baseline (534.128 us; speedup 1.0000x reference)
//
#include <hip/hip_runtime.h>

// pose3d_future loss, round 3: wave-cooperative, fully-coalesced loads.
// One sample per wave-iteration: lanes 0..62 hold the sample's 63 pose floats
// (ONE coalesced dword load = 252 contiguous bytes), lanes 0..41 hold the 42
// est floats. In-register transpose via __shfl (ds_bpermute), joints computed
// on lanes 0..20, per-lane accumulation across samples. Depth-2 prefetch for
// MLP; 8192 waves with interleaved sample assignment (stride = #waves) for
// balance + compact L2 window.
// R2 failure mode fixed: no 252-B-strided scattered lanes, no compiler
// load-sinking (prefetch regs have no use until next iteration).

namespace {

constexpr float F_    = 525.0f;
constexpr float CX_   = 320.0f;
constexpr float CY_   = 240.0f;
constexpr float WPROJ = 0.33f / 42.0f;   // W_PROJ / (2*J)
constexpr float WBONE = 0.5f  / 20.0f;   // W_BONE / (J-1)
constexpr int   NT    = 256;             // 4 waves / block
constexpr int   NBLK  = 2048;            // 8192 waves = 8 waves/SIMD available
constexpr int   NW    = NBLK * NT / 64;  // total waves

__global__ __launch_bounds__(NT, 6)
void pose_loss_kernel(const float* __restrict__ pose,   // [B,3,21]
                      const float* __restrict__ est,    // [B,2,21]
                      const float* __restrict__ bl,     // [20]
                      const float* __restrict__ Rm,     // [3,3]
                      const float* __restrict__ Cd,     // [3,1]
                      float* __restrict__ out,
                      int B)
{
    const int lane = threadIdx.x & 63;
    const int wid  = (int)((blockIdx.x * NT + threadIdx.x) >> 6);  // global wave

    // ---- uniform camera params: M = K @ R^T ----
    const float r0 = Rm[0], r1 = Rm[1], r2 = Rm[2];
    const float r3 = Rm[3], r4 = Rm[4], r5 = Rm[5];
    const float r6 = Rm[6], r7 = Rm[7], r8 = Rm[8];
    const float m00 = F_ * r0 + CX_ * r2;
    const float m01 = F_ * r3 + CX_ * r5;
    const float m02 = F_ * r6 + CX_ * r8;
    const float m10 = F_ * r1 + CY_ * r2;
    const float m11 = F_ * r4 + CY_ * r5;
    const float m12 = F_ * r7 + CY_ * r8;
    const float m20 = r2, m21 = r5, m22 = r8;
    const float c0 = Cd[0], c1 = Cd[1], c2 = Cd[2];

    // per-lane bone target: lane j (1..20) computes bone j -> bl[j-1]
    int bli = lane - 1; bli = bli < 0 ? 0 : (bli > 19 ? 19 : bli);
    const float blv = bl[bli];

    const bool projActive = lane < 21;
    const bool boneActive = (lane >= 1) && (lane <= 20);

    // clamped load lanes (avoid OOB without predication -> loads hoistable)
    const int pl = lane < 63 ? lane : 62;
    const int el = lane < 42 ? lane : 41;

    float accP = 0.0f, accB = 0.0f;

    if (wid < B) {
        const int n = (B - 1 - wid) / NW + 1;   // samples for this wave
        const long sLast = (long)wid + (long)(n - 1) * NW;

        // depth-2 prefetch
        long s1 = (long)wid + NW; if (s1 > sLast) s1 = sLast;
        float p0 = pose[(long)wid * 63 + pl];
        float e0 = est [(long)wid * 42 + el];
        float p1 = pose[s1 * 63 + pl];
        float e1 = est [s1 * 42 + el];

        for (int i = 0; i < n; ++i) {
            long s2 = (long)wid + (long)(i + 2) * NW;
            if (s2 > sLast) s2 = sLast;
            const float p2 = pose[s2 * 63 + pl];
            const float e2 = est [s2 * 42 + el];

            // ---- in-register transpose (sample layout: x0..x20 y0..y20 z0..z20)
            const float y_raw = __shfl(p0, lane + 21, 64);   // y_j
            const float z_raw = __shfl(p0, lane + 42, 64);   // z_j
            const float xp    = __shfl(p0, lane - 1,  64);   // x_{j-1}
            const float yp    = __shfl(p0, lane + 20, 64);   // y_{j-1}
            const float zp    = __shfl(p0, lane + 41, 64);   // z_{j-1}
            const float v     = __shfl(e0, lane + 21, 64);   // v_j
            const float u     = e0;                          // u_j
            const float praw  = p0;                          // x_j

            // ---- projection ----
            const float x = praw  - c0;
            const float y = y_raw - c1;
            const float z = z_raw - c2;
            const float q0 = m00 * x + m01 * y + m02 * z;
            const float q1 = m10 * x + m11 * y + m12 * z;
            const float q2 = m20 * x + m21 * y + m22 * z;
            const float inv = __builtin_amdgcn_rcpf(q2);     // z ~ 10, safe
            const float du = q0 * inv - u;
            const float dv = q1 * inv - v;
            const float pt = du * du + dv * dv;
            accP += projActive ? pt : 0.0f;                  // select kills NaN/inf

            // ---- bone (camera offset cancels in the diff: use raw coords) ----
            const float dx = xp - praw;
            const float dy = yp - y_raw;
            const float dz = zp - z_raw;
            const float sq = dx * dx + dy * dy + dz * dz;
            float err = blv - sq;
            err = boneActive ? err : 0.0f;
            accB = fmaf(err, err, accB);

            p0 = p1; e0 = e1; p1 = p2; e1 = e2;
        }
    }

    // ---- wave reduction + one atomic per wave ----
    float acc = WPROJ * accP + WBONE * accB;
    #pragma unroll
    for (int off = 32; off > 0; off >>= 1)
        acc += __shfl_down(acc, off, 64);
    if (lane == 0)
        atomicAdd(out, acc * (1.0f / (float)B));
}

} // namespace

extern "C" void kernel_launch(void* const* d_in, const int* in_sizes, int n_in,
                              void* d_out, int out_size, void* d_ws, size_t ws_size,
                              hipStream_t stream) {
    const float* pose = (const float*)d_in[0];
    const float* est  = (const float*)d_in[1];
    const float* bl   = (const float*)d_in[2];
    const float* Rm   = (const float*)d_in[3];
    const float* Cd   = (const float*)d_in[4];
    float* out = (float*)d_out;

    const int B = in_sizes[0] / 63;               // [B,3,21] flat

    hipMemsetAsync(out, 0, sizeof(float), stream);  // d_out is poisoned 0xAA
    pose_loss_kernel<<<NBLK, NT, 0, stream>>>(pose, est, bl, Rm, Cd, out, B);
}

// Round 4
// 441.720 us; speedup vs baseline: 1.2092x; 1.2092x over previous
//
#include <hip/hip_runtime.h>

// pose3d_future loss, round 4: async-DMA double-buffered LDS pipeline.
// R3 lesson (cache-resident replays at identical 227 us): per-sample bpermute
// transpose saturates the LDS crossbar. Here the LDS pipe moves data in fully-
// used 1 KB ds_read/global_load_lds chunks instead.
// Structure: single-wave (64-thread) persistent blocks, 64-sample tiles,
// global_load_lds width=16 into a double buffer, manual s_waitcnt vmcnt(27)
// so tile i+1 streams from HBM while tile i computes. No barriers (one wave),
// so the compiler cannot inject the vmcnt(0)-before-s_barrier drain.
// 53.8 KB static LDS -> 3 blocks/CU; outstanding DMA (~1-2 tiles/block) is the
// latency hider, not wave count.

namespace {

constexpr float F_    = 525.0f;
constexpr float CX_   = 320.0f;
constexpr float CY_   = 240.0f;
constexpr float WPROJ = 0.33f / 42.0f;   // W_PROJ / (2*J)
constexpr float WBONE = 0.5f  / 20.0f;   // W_BONE / (J-1)
constexpr int   NT    = 64;              // one wave per block
constexpr int   TILE  = 64;              // samples per tile
constexpr int   PF4   = TILE * 63 / 4;   // 1008 float4 of pose per tile
constexpr int   EF4   = TILE * 42 / 4;   // 672  float4 of est  per tile
constexpr int   TF4   = PF4 + EF4;       // 1680 float4 per tile (26880 B)
constexpr int   RFULL = TF4 / NT;        // 26 full DMA rounds
constexpr int   REM   = TF4 - RFULL*NT;  // 16-lane remainder round
constexpr int   DMA_N = RFULL + 1;       // 27 vm events per wave per tile
constexpr int   NBLK  = 768;             // 3 single-wave blocks per CU

// gfx9/CDNA s_waitcnt imm: vmcnt[3:0]=b[3:0], vmcnt[5:4]=b[15:14],
// expcnt=b[6:4] (7=no wait), lgkmcnt=b[11:8] (15=no wait).
constexpr int wcnt(int vm, int lgkm) {
    return (vm & 0xF) | ((vm >> 4) << 14) | (0x7 << 4) | ((lgkm & 0xF) << 8);
}

__device__ __forceinline__ long lmin(long a, long b) { return a < b ? a : b; }

__global__ __launch_bounds__(NT)
void pose_loss_kernel(const float* __restrict__ pose,   // [B,3,21]
                      const float* __restrict__ est,    // [B,2,21]
                      const float* __restrict__ bl,     // [20]
                      const float* __restrict__ Rm,     // [3,3]
                      const float* __restrict__ Cd,     // [3,1]
                      float* __restrict__ out,
                      int B)
{
    __shared__ float4 smem[2 * TF4];     // 53760 B

    const int tid = threadIdx.x;
    const float4* pose4 = (const float4*)pose;
    const float4* est4  = (const float4*)est;
    const long pmax = (long)B * 63 / 4 - 1;   // clamp: stay in-bounds on tail
    const long emax = (long)B * 42 / 4 - 1;
    const int  ntiles = (B + TILE - 1) / TILE;

    // ---- uniform camera params: M = K @ R^T ----
    const float r0 = Rm[0], r1 = Rm[1], r2 = Rm[2];
    const float r3 = Rm[3], r4 = Rm[4], r5 = Rm[5];
    const float r6 = Rm[6], r7 = Rm[7], r8 = Rm[8];
    const float m00 = F_ * r0 + CX_ * r2;
    const float m01 = F_ * r3 + CX_ * r5;
    const float m02 = F_ * r6 + CX_ * r8;
    const float m10 = F_ * r1 + CY_ * r2;
    const float m11 = F_ * r4 + CY_ * r5;
    const float m12 = F_ * r7 + CY_ * r8;
    const float m20 = r2, m21 = r5, m22 = r8;
    const float c0 = Cd[0], c1 = Cd[1], c2 = Cd[2];
    float blv[20];
    #pragma unroll
    for (int i = 0; i < 20; ++i) blv[i] = bl[i];   // uniform -> SGPRs

    // ---- async DMA of one 64-sample tile into LDS buffer `buf` ----
    auto dma = [&](long T, int buf) {
        const long pb = T * PF4;
        const long eb = T * EF4 - PF4;            // so est idx = eb + f
        float4* dst = &smem[buf * TF4];
        #pragma unroll
        for (int r = 0; r < RFULL; ++r) {
            const int f = r * NT + tid;
            // per-lane pointer select (single load instr -> exact vm count)
            const float4* g = (f < PF4) ? (pose4 + lmin(pb + f, pmax))
                                        : (est4  + lmin(eb + f, emax));
            __builtin_amdgcn_global_load_lds(
                (const __attribute__((address_space(1))) void*)g,
                (__attribute__((address_space(3))) void*)(dst + r * NT),
                16, 0, 0);
        }
        if (tid < REM) {                          // last 16 float4 (est region)
            const long gi = lmin(eb + RFULL * NT + tid, emax);
            __builtin_amdgcn_global_load_lds(
                (const __attribute__((address_space(1))) void*)(est4 + gi),
                (__attribute__((address_space(3))) void*)(&smem[buf*TF4 + RFULL*NT]),
                16, 0, 0);
        }
    };

    float accP = 0.0f, accB = 0.0f;
    long T = blockIdx.x;
    if (T < ntiles) dma(T, 0);

    int i = 0;
    while (T < ntiles) {
        const long Tn = T + NBLK;
        __asm__ __volatile__("" ::: "memory");
        // my ds_reads of the buffer about to be overwritten are long retired;
        // belt-and-braces lgkm drain before issuing the overwriting DMA.
        __builtin_amdgcn_s_waitcnt(wcnt(63, 0));
        if (Tn < ntiles) {
            dma(Tn, (i + 1) & 1);                          // +27 in flight
            __builtin_amdgcn_s_waitcnt(wcnt(DMA_N, 15));   // tile T landed,
        } else {                                           // tile Tn still flying
            __builtin_amdgcn_s_waitcnt(wcnt(0, 15));       // tail: full drain
        }
        __asm__ __volatile__("" ::: "memory");

        // ---- compute tile T from LDS buffer i&1 (1 thread : 1 sample) ----
        const float* sm = (const float*)&smem[(i & 1) * TF4];
        const float* ps = sm + tid * 63;             // x0..20 y0..20 z0..20
        const float* es = sm + TILE * 63 + tid * 42; // u0..20 v0..20
        const bool valid = (T * TILE + tid) < (long)B;
        float proj = 0.0f, bone = 0.0f;
        float pvx = 0.f, pvy = 0.f, pvz = 0.f;
        #pragma unroll
        for (int j = 0; j < 21; ++j) {
            const float x = ps[j]      - c0;
            const float y = ps[21 + j] - c1;
            const float z = ps[42 + j] - c2;
            const float q0 = fmaf(m00, x, fmaf(m01, y, m02 * z));
            const float q1 = fmaf(m10, x, fmaf(m11, y, m12 * z));
            const float q2 = fmaf(m20, x, fmaf(m21, y, m22 * z));
            const float inv = __builtin_amdgcn_rcpf(q2);   // z ~ 10, safe
            const float du = fmaf(q0, inv, -es[j]);
            const float dv = fmaf(q1, inv, -es[21 + j]);
            proj += du * du + dv * dv;
            if (j > 0) {                 // chain bone (j-1, j); C cancels
                const float dx = pvx - x, dy = pvy - y, dz = pvz - z;
                const float sq = dx * dx + dy * dy + dz * dz;
                const float e  = blv[j - 1] - sq;
                bone += e * e;
            }
            pvx = x; pvy = y; pvz = z;
        }
        accP += valid ? proj : 0.0f;     // select also kills tail NaN/inf
        accB += valid ? bone : 0.0f;

        T = Tn; ++i;
    }

    // ---- wave reduction + one atomic per block ----
    float acc = WPROJ * accP + WBONE * accB;
    #pragma unroll
    for (int off = 32; off > 0; off >>= 1)
        acc += __shfl_down(acc, off, 64);
    if (tid == 0)
        atomicAdd(out, acc * (1.0f / (float)B));
}

} // namespace

extern "C" void kernel_launch(void* const* d_in, const int* in_sizes, int n_in,
                              void* d_out, int out_size, void* d_ws, size_t ws_size,
                              hipStream_t stream) {
    const float* pose = (const float*)d_in[0];
    const float* est  = (const float*)d_in[1];
    const float* bl   = (const float*)d_in[2];
    const float* Rm   = (const float*)d_in[3];
    const float* Cd   = (const float*)d_in[4];
    float* out = (float*)d_out;

    const int B = in_sizes[0] / 63;               // [B,3,21] flat

    hipMemsetAsync(out, 0, sizeof(float), stream);  // d_out is poisoned 0xAA
    pose_loss_kernel<<<NBLK, NT, 0, stream>>>(pose, est, bl, Rm, Cd, out, B);
}